// Round 1
// baseline (1196.382 us; speedup 1.0000x reference)
//
#include <hip/hip_runtime.h>
#include <stdint.h>
#include <stddef.h>

// Pipeline:
//  k_conv_x : x fp32 -> xbf bf16 [N][256]
//  k_wt     : W [256][1024] -> Wt bf16 [1024][256] (transposed)
//  k_init   : mEnc=-inf enc, denom=0, head=-1, pooled=0
//  k_link   : per-dst linked lists over original edges (atomicExch)
//  k_gemm   : xw[N][1024] = x@W via mfma_f32_16x16x32_bf16, store bf16
//  k_attn   : a_s[n,h]=<xw,att_src>, a_d[n,h]=<xw,att_dst>, s_row[n,h]=rowsum
//  k_max    : segment max over dst (float-as-uint atomicMax), incl self-loops
//  k_dec    : decode encoded max to float
//  k_denom  : denom[dst,h] += exp(logit - m)
//  k_pool   : pooled[h] = sum_e alpha * s_row[src]   (block-reduced atomics)
//  k_head   : a[h] = softmax(relu(pooled/(N*C)+biasmean)*cw+cb), hb[c]=sum_h a[h]bias
//  k_fuse   : per node (1 wave): h[n,c] = relu(sum_edges sum_h a[h]*alpha*xw[src,h,c] + hb + x)
//  k_out    : per edge (1 wave): out = log_softmax((h[s]*h[d]) @ linW + b)

typedef short bf16x8 __attribute__((ext_vector_type(8)));
typedef float f32x4 __attribute__((ext_vector_type(4)));
typedef unsigned short u16x8 __attribute__((ext_vector_type(8)));
typedef unsigned short u16x4 __attribute__((ext_vector_type(4)));

__device__ __forceinline__ unsigned short f2bf(float f) {
  unsigned u = __float_as_uint(f);
  u += 0x7FFFu + ((u >> 16) & 1u);
  return (unsigned short)(u >> 16);
}
__device__ __forceinline__ float bf2f(unsigned short s) {
  return __uint_as_float(((unsigned)s) << 16);
}
__device__ __forceinline__ unsigned fenc(float f) {
  unsigned b = __float_as_uint(f);
  return (b & 0x80000000u) ? ~b : (b | 0x80000000u);
}
__device__ __forceinline__ float fdec(unsigned u) {
  unsigned b = (u & 0x80000000u) ? (u & 0x7FFFFFFFu) : ~u;
  return __uint_as_float(b);
}
__device__ __forceinline__ float lrelu(float v) { return v >= 0.f ? v : 0.2f * v; }

__device__ __forceinline__ void gload16(const void* g, void* l) {
  __builtin_amdgcn_global_load_lds((const __attribute__((address_space(1))) void*)g,
                                   (__attribute__((address_space(3))) void*)l, 16, 0, 0);
}

// ---------------- conversion kernels ----------------
__global__ __launch_bounds__(256) void k_conv_x(const float* __restrict__ x,
                                                unsigned short* __restrict__ xbf, int total8) {
  int i = blockIdx.x * 256 + threadIdx.x;
  if (i >= total8) return;
  const float4* xp = (const float4*)x;
  float4 a = xp[2 * (size_t)i], b = xp[2 * (size_t)i + 1];
  u16x8 o;
  o[0] = f2bf(a.x); o[1] = f2bf(a.y); o[2] = f2bf(a.z); o[3] = f2bf(a.w);
  o[4] = f2bf(b.x); o[5] = f2bf(b.y); o[6] = f2bf(b.z); o[7] = f2bf(b.w);
  *(u16x8*)(xbf + (size_t)i * 8) = o;
}

__global__ __launch_bounds__(256) void k_wt(const float* __restrict__ W,
                                            unsigned short* __restrict__ wt) {
  int m = blockIdx.x * 256 + threadIdx.x;  // 0..1023
  for (int k = 0; k < 256; ++k) wt[(size_t)m * 256 + k] = f2bf(W[(size_t)k * 1024 + m]);
}

// ---------------- init + edge lists ----------------
__global__ __launch_bounds__(256) void k_init(unsigned* __restrict__ mEnc, float* __restrict__ denom,
                                              int* __restrict__ head, float* __restrict__ pooled, int n) {
  int i = blockIdx.x * 256 + threadIdx.x;
  if (i < n * 4) { mEnc[i] = 0x007FFFFFu; denom[i] = 0.f; }
  if (i < n) head[i] = -1;
  if (i < 4) pooled[i] = 0.f;
}

__global__ __launch_bounds__(256) void k_link(const int* __restrict__ ei, int* __restrict__ head,
                                              int* __restrict__ nxt, int E) {
  int e = blockIdx.x * 256 + threadIdx.x;
  if (e >= E) return;
  int dst = ei[E + e];
  nxt[e] = atomicExch(&head[dst], e);
}

// ---------------- GEMM: xw = x @ W (bf16 MFMA 16x16x32) ----------------
__global__ __launch_bounds__(256) void k_gemm(const unsigned short* __restrict__ A,   // [NR][256] bf16
                                              const unsigned short* __restrict__ Bt,  // [1024][256] bf16 (W^T)
                                              unsigned short* __restrict__ C,         // [NR][1024] bf16
                                              int NR) {
  __shared__ unsigned short sm[8192];  // As[128][32] + Bs[128][32]
  unsigned short* As = sm;
  unsigned short* Bs = sm + 4096;
  const int t = threadIdx.x;
  const int w = t >> 6, lane = t & 63;
  const int wm = w >> 1, wn = w & 1;
  const int m0 = blockIdx.x * 128;
  const int n0 = blockIdx.y * 128;

  f32x4 acc[4][4];
#pragma unroll
  for (int i = 0; i < 4; ++i)
#pragma unroll
    for (int j = 0; j < 4; ++j) acc[i][j] = (f32x4){0.f, 0.f, 0.f, 0.f};

  // staging geometry: per wave two 1KB chunks per matrix; HW puts lane l at base+16*l
  const int rQ = lane >> 2;  // row within 16-row chunk
  const int cQ = lane & 3;   // 16B chunk within 64B row
  const int rA0 = (w * 2 + 0) * 16 + rQ;
  const int rA1 = (w * 2 + 1) * 16 + rQ;
  const int scA0 = cQ ^ (rA0 & 3);   // source-side XOR swizzle (read applies same XOR)
  const int scA1 = cQ ^ (rA1 & 3);
  const int gA0 = min(m0 + rA0, NR - 1);
  const int gA1 = min(m0 + rA1, NR - 1);
  const int gB0 = n0 + rA0;
  const int gB1 = n0 + rA1;

  const int kc = lane >> 4;
  const int rl = lane & 15;

#pragma unroll 1
  for (int kk = 0; kk < 8; ++kk) {
    const int k0 = kk * 32;
    gload16(A + (size_t)gA0 * 256 + k0 + scA0 * 8, &As[(w * 2 + 0) * 512]);
    gload16(A + (size_t)gA1 * 256 + k0 + scA1 * 8, &As[(w * 2 + 1) * 512]);
    gload16(Bt + (size_t)gB0 * 256 + k0 + scA0 * 8, &Bs[(w * 2 + 0) * 512]);
    gload16(Bt + (size_t)gB1 * 256 + k0 + scA1 * 8, &Bs[(w * 2 + 1) * 512]);
    __syncthreads();
    bf16x8 aF[4], bF[4];
#pragma unroll
    for (int mi = 0; mi < 4; ++mi) {
      int row = wm * 64 + mi * 16 + rl;
      aF[mi] = *(const bf16x8*)&As[row * 32 + ((kc * 8) ^ ((row & 3) * 8))];
    }
#pragma unroll
    for (int ni = 0; ni < 4; ++ni) {
      int row = wn * 64 + ni * 16 + rl;
      bF[ni] = *(const bf16x8*)&Bs[row * 32 + ((kc * 8) ^ ((row & 3) * 8))];
    }
#pragma unroll
    for (int mi = 0; mi < 4; ++mi)
#pragma unroll
      for (int ni = 0; ni < 4; ++ni)
        acc[mi][ni] = __builtin_amdgcn_mfma_f32_16x16x32_bf16(aF[mi], bF[ni], acc[mi][ni], 0, 0, 0);
    __syncthreads();
  }

#pragma unroll
  for (int mi = 0; mi < 4; ++mi)
#pragma unroll
    for (int j = 0; j < 4; ++j) {
      int row = m0 + wm * 64 + mi * 16 + (lane >> 4) * 4 + j;
      if (row < NR) {
#pragma unroll
        for (int ni = 0; ni < 4; ++ni) {
          int col = n0 + wn * 64 + ni * 16 + rl;
          C[(size_t)row * 1024 + col] = f2bf(acc[mi][ni][j]);
        }
      }
    }
}

// ---------------- per-node attention scalars ----------------
__global__ __launch_bounds__(256) void k_attn(const unsigned short* __restrict__ xwbf,
                                              const float* __restrict__ att_s,
                                              const float* __restrict__ att_d,
                                              float* __restrict__ a_s, float* __restrict__ a_d,
                                              float* __restrict__ s_row) {
  int node = blockIdx.x;
  int t = threadIdx.x, w = t >> 6, lane = t & 63;
  __shared__ float red[4][4][3];
  const unsigned short* rowp = xwbf + (size_t)node * 1024;
#pragma unroll
  for (int h = 0; h < 4; ++h) {
    float v = bf2f(rowp[h * 256 + t]);
    float ps = v * att_s[h * 256 + t];
    float pd = v * att_d[h * 256 + t];
    float pr = v;
#pragma unroll
    for (int o = 32; o >= 1; o >>= 1) {
      ps += __shfl_xor(ps, o);
      pd += __shfl_xor(pd, o);
      pr += __shfl_xor(pr, o);
    }
    if (lane == 0) { red[h][w][0] = ps; red[h][w][1] = pd; red[h][w][2] = pr; }
  }
  __syncthreads();
  if (t < 4) {
    float ps = 0, pd = 0, pr = 0;
    for (int ww = 0; ww < 4; ++ww) { ps += red[t][ww][0]; pd += red[t][ww][1]; pr += red[t][ww][2]; }
    a_s[(size_t)node * 4 + t] = ps;
    a_d[(size_t)node * 4 + t] = pd;
    s_row[(size_t)node * 4 + t] = pr;
  }
}

// ---------------- segment max / denom / pooled ----------------
__global__ __launch_bounds__(256) void k_max(const int* __restrict__ ei, const float* __restrict__ a_s,
                                             const float* __restrict__ a_d, unsigned* __restrict__ mEnc,
                                             int E, int n) {
  int e = blockIdx.x * 256 + threadIdx.x;
  int tot = E + n;
  if (e >= tot) return;
  int src = e < E ? ei[e] : (e - E);
  int dst = e < E ? ei[E + e] : (e - E);
  float asv[4], adv[4];
  *(float4*)asv = *(const float4*)(a_s + (size_t)src * 4);
  *(float4*)adv = *(const float4*)(a_d + (size_t)dst * 4);
#pragma unroll
  for (int h = 0; h < 4; ++h) {
    float lg = lrelu(asv[h] + adv[h]);
    atomicMax(&mEnc[(size_t)dst * 4 + h], fenc(lg));
  }
}

__global__ __launch_bounds__(256) void k_dec(const unsigned* __restrict__ mEnc,
                                             float* __restrict__ mFlt, int n4) {
  int i = blockIdx.x * 256 + threadIdx.x;
  if (i < n4) mFlt[i] = fdec(mEnc[i]);
}

__global__ __launch_bounds__(256) void k_denom(const int* __restrict__ ei, const float* __restrict__ a_s,
                                               const float* __restrict__ a_d, const float* __restrict__ mFlt,
                                               float* __restrict__ denom, int E, int n) {
  int e = blockIdx.x * 256 + threadIdx.x;
  int tot = E + n;
  if (e >= tot) return;
  int src = e < E ? ei[e] : (e - E);
  int dst = e < E ? ei[E + e] : (e - E);
  float asv[4], adv[4], mv[4];
  *(float4*)asv = *(const float4*)(a_s + (size_t)src * 4);
  *(float4*)adv = *(const float4*)(a_d + (size_t)dst * 4);
  *(float4*)mv = *(const float4*)(mFlt + (size_t)dst * 4);
#pragma unroll
  for (int h = 0; h < 4; ++h) {
    float p = expf(lrelu(asv[h] + adv[h]) - mv[h]);
    atomicAdd(&denom[(size_t)dst * 4 + h], p);
  }
}

__global__ __launch_bounds__(256) void k_pool(const int* __restrict__ ei, const float* __restrict__ a_s,
                                              const float* __restrict__ a_d, const float* __restrict__ mFlt,
                                              const float* __restrict__ denom, const float* __restrict__ s_row,
                                              float* __restrict__ pooled, int E, int n) {
  int e = blockIdx.x * 256 + threadIdx.x;
  int lane = threadIdx.x & 63;
  int tot = E + n;
  bool valid = e < tot;
  float ph[4] = {0.f, 0.f, 0.f, 0.f};
  if (valid) {
    int src = e < E ? ei[e] : (e - E);
    int dst = e < E ? ei[E + e] : (e - E);
    float asv[4], adv[4], mv[4], dv[4], sv[4];
    *(float4*)asv = *(const float4*)(a_s + (size_t)src * 4);
    *(float4*)adv = *(const float4*)(a_d + (size_t)dst * 4);
    *(float4*)mv = *(const float4*)(mFlt + (size_t)dst * 4);
    *(float4*)dv = *(const float4*)(denom + (size_t)dst * 4);
    *(float4*)sv = *(const float4*)(s_row + (size_t)src * 4);
#pragma unroll
    for (int h = 0; h < 4; ++h) {
      float p = expf(lrelu(asv[h] + adv[h]) - mv[h]);
      ph[h] = p / (dv[h] + 1e-16f) * sv[h];
    }
  }
#pragma unroll
  for (int h = 0; h < 4; ++h) {
#pragma unroll
    for (int o = 32; o >= 1; o >>= 1) ph[h] += __shfl_xor(ph[h], o);
  }
  if (lane == 0) {
#pragma unroll
    for (int h = 0; h < 4; ++h) atomicAdd(&pooled[h], ph[h]);
  }
}

// ---------------- head gate + fused bias ----------------
__global__ __launch_bounds__(256) void k_head(const float* __restrict__ pooled,
                                              const float* __restrict__ gbias,
                                              const float* __restrict__ cw, const float* __restrict__ cb,
                                              float* __restrict__ a4, float* __restrict__ hb, int n) {
  __shared__ float red[4][4];
  __shared__ float aa[4];
  int t = threadIdx.x, w = t >> 6, lane = t & 63;
#pragma unroll
  for (int h = 0; h < 4; ++h) {
    float v = gbias[h * 256 + t];
#pragma unroll
    for (int o = 32; o >= 1; o >>= 1) v += __shfl_xor(v, o);
    if (lane == 0) red[h][w] = v;
  }
  __syncthreads();
  if (t == 0) {
    float q[4], mx = -1e30f;
    for (int h = 0; h < 4; ++h) {
      float bm = (red[h][0] + red[h][1] + red[h][2] + red[h][3]) * (1.f / 256.f);
      float pl = pooled[h] / ((float)n * 256.f) + bm;
      float c = pl * cw[0] + cb[0];
      c = fmaxf(c, 0.f);
      q[h] = c;
      mx = fmaxf(mx, c);
    }
    float sum = 0.f;
    for (int h = 0; h < 4; ++h) { q[h] = expf(q[h] - mx); sum += q[h]; }
    for (int h = 0; h < 4; ++h) { aa[h] = q[h] / sum; a4[h] = aa[h]; }
  }
  __syncthreads();
  float hbv = 0.f;
  for (int h = 0; h < 4; ++h) hbv += aa[h] * gbias[h * 256 + t];
  hb[t] = hbv;
}

// ---------------- per-node fused aggregation -> h ----------------
__global__ __launch_bounds__(256) void k_fuse(const int* __restrict__ ei,
                                              const unsigned short* __restrict__ xwbf,
                                              const float* __restrict__ a_s, const float* __restrict__ a_d,
                                              const float* __restrict__ mFlt, const float* __restrict__ denom,
                                              const int* __restrict__ head, const int* __restrict__ nxt,
                                              const float* __restrict__ a4, const float* __restrict__ hb,
                                              const float* __restrict__ x, float* __restrict__ hbuf, int n) {
  int node = blockIdx.x * 4 + (threadIdx.x >> 6);
  int lane = threadIdx.x & 63;
  if (node >= n) return;
  float adv[4], mv[4], dv[4], av[4];
  *(float4*)adv = *(const float4*)(a_d + (size_t)node * 4);
  *(float4*)mv = *(const float4*)(mFlt + (size_t)node * 4);
  *(float4*)dv = *(const float4*)(denom + (size_t)node * 4);
  *(float4*)av = *(const float4*)a4;
  float acc0 = 0.f, acc1 = 0.f, acc2 = 0.f, acc3 = 0.f;
  const int c0 = lane * 4;
  int j = node;  // self-loop first
  int e = -2;
  while (true) {
    float asv[4];
    *(float4*)asv = *(const float4*)(a_s + (size_t)j * 4);
    float ws[4];
#pragma unroll
    for (int h = 0; h < 4; ++h) {
      float p = expf(lrelu(asv[h] + adv[h]) - mv[h]);
      ws[h] = av[h] * p / (dv[h] + 1e-16f);
    }
    const unsigned short* rp = xwbf + (size_t)j * 1024;
#pragma unroll
    for (int h = 0; h < 4; ++h) {
      u16x4 q = *(const u16x4*)(rp + h * 256 + c0);
      acc0 += ws[h] * bf2f(q[0]);
      acc1 += ws[h] * bf2f(q[1]);
      acc2 += ws[h] * bf2f(q[2]);
      acc3 += ws[h] * bf2f(q[3]);
    }
    e = (e == -2) ? head[node] : nxt[e];
    if (e < 0) break;
    j = ei[e];
  }
  float4 xb = *(const float4*)(x + (size_t)node * 256 + c0);
  float4 hbv = *(const float4*)(hb + c0);
  float4 o;
  o.x = fmaxf(acc0 + hbv.x + xb.x, 0.f);
  o.y = fmaxf(acc1 + hbv.y + xb.y, 0.f);
  o.z = fmaxf(acc2 + hbv.z + xb.z, 0.f);
  o.w = fmaxf(acc3 + hbv.w + xb.w, 0.f);
  *(float4*)(hbuf + (size_t)node * 256 + c0) = o;
}

// ---------------- edge classifier + log_softmax ----------------
__global__ __launch_bounds__(256) void k_out(const int* __restrict__ ei, const float* __restrict__ hbuf,
                                             const float* __restrict__ linW, const float* __restrict__ linb,
                                             float* __restrict__ out, int E) {
  int gw = blockIdx.x * 4 + (threadIdx.x >> 6);
  int lane = threadIdx.x & 63;
  if (gw >= E) return;
  int src = ei[gw], dst = ei[E + gw];
  const int c0 = lane * 4;
  float4 hs = *(const float4*)(hbuf + (size_t)src * 256 + c0);
  float4 hd = *(const float4*)(hbuf + (size_t)dst * 256 + c0);
  float4 wa = *(const float4*)(linW + (size_t)c0 * 2);       // (c0,0),(c0,1),(c0+1,0),(c0+1,1)
  float4 wb = *(const float4*)(linW + (size_t)c0 * 2 + 4);   // (c0+2,0),(c0+2,1),(c0+3,0),(c0+3,1)
  float e0 = hs.x * hd.x, e1 = hs.y * hd.y, e2 = hs.z * hd.z, e3 = hs.w * hd.w;
  float u0 = e0 * wa.x + e1 * wa.z + e2 * wb.x + e3 * wb.z;
  float u1 = e0 * wa.y + e1 * wa.w + e2 * wb.y + e3 * wb.w;
#pragma unroll
  for (int o = 32; o >= 1; o >>= 1) {
    u0 += __shfl_xor(u0, o);
    u1 += __shfl_xor(u1, o);
  }
  if (lane == 0) {
    u0 += linb[0];
    u1 += linb[1];
    float mx = fmaxf(u0, u1);
    float lse = mx + logf(expf(u0 - mx) + expf(u1 - mx));
    float2 r;
    r.x = u0 - lse;
    r.y = u1 - lse;
    *(float2*)(out + (size_t)gw * 2) = r;
  }
}

// ---------------- launch ----------------
extern "C" void kernel_launch(void* const* d_in, const int* in_sizes, int n_in,
                              void* d_out, int out_size, void* d_ws, size_t ws_size,
                              hipStream_t stream) {
  const float* x = (const float*)d_in[0];
  const int* ei = (const int*)d_in[1];
  const float* W = (const float*)d_in[2];
  const float* att_s = (const float*)d_in[3];
  const float* att_d = (const float*)d_in[4];
  const float* gbias = (const float*)d_in[5];
  const float* cw = (const float*)d_in[6];
  const float* cb = (const float*)d_in[7];
  const float* linW = (const float*)d_in[8];
  const float* linb = (const float*)d_in[9];
  float* out = (float*)d_out;

  const int n = in_sizes[0] / 256;   // 100000
  const int E = in_sizes[1] / 2;     // 300000
  const int tot = E + n;

  char* p = (char*)d_ws;
  auto alloc = [&](size_t bytes) -> char* {
    char* r = p;
    p += (bytes + 255) & ~(size_t)255;
    return r;
  };
  unsigned short* xwbf = (unsigned short*)alloc((size_t)n * 1024 * 2);
  unsigned short* xbf = (unsigned short*)alloc((size_t)n * 256 * 2);
  unsigned short* wtbf = (unsigned short*)alloc((size_t)1024 * 256 * 2);
  float* a_s = (float*)alloc((size_t)n * 4 * 4);
  float* a_d = (float*)alloc((size_t)n * 4 * 4);
  float* s_row = (float*)alloc((size_t)n * 4 * 4);
  unsigned* mEnc = (unsigned*)alloc((size_t)n * 4 * 4);
  float* mFlt = (float*)alloc((size_t)n * 4 * 4);
  float* denom = (float*)alloc((size_t)n * 4 * 4);
  int* head = (int*)alloc((size_t)n * 4);
  int* nxt = (int*)alloc((size_t)E * 4);
  float* pooled = (float*)alloc(256);
  float* a4 = (float*)alloc(256);
  float* hb = (float*)alloc(256 * 4);
  float* hbuf = (float*)alloc((size_t)n * 256 * 4);

  int total8 = n * 256 / 8;
  k_conv_x<<<dim3((total8 + 255) / 256), dim3(256), 0, stream>>>(x, xbf, total8);
  k_wt<<<dim3(4), dim3(256), 0, stream>>>(W, wtbf);
  k_init<<<dim3((n * 4 + 255) / 256), dim3(256), 0, stream>>>(mEnc, denom, head, pooled, n);
  k_link<<<dim3((E + 255) / 256), dim3(256), 0, stream>>>(ei, head, nxt, E);
  k_gemm<<<dim3((n + 127) / 128, 8), dim3(256), 0, stream>>>(xbf, wtbf, xwbf, n);
  k_attn<<<dim3(n), dim3(256), 0, stream>>>(xwbf, att_s, att_d, a_s, a_d, s_row);
  k_max<<<dim3((tot + 255) / 256), dim3(256), 0, stream>>>(ei, a_s, a_d, mEnc, E, n);
  k_dec<<<dim3((n * 4 + 255) / 256), dim3(256), 0, stream>>>(mEnc, mFlt, n * 4);
  k_denom<<<dim3((tot + 255) / 256), dim3(256), 0, stream>>>(ei, a_s, a_d, mFlt, denom, E, n);
  k_pool<<<dim3((tot + 255) / 256), dim3(256), 0, stream>>>(ei, a_s, a_d, mFlt, denom, s_row, pooled, E, n);
  k_head<<<dim3(1), dim3(256), 0, stream>>>(pooled, gbias, cw, cb, a4, hb, n);
  k_fuse<<<dim3((n + 3) / 4), dim3(256), 0, stream>>>(ei, xwbf, a_s, a_d, mFlt, denom, head, nxt, a4, hb, x, hbuf, n);
  k_out<<<dim3((E + 3) / 4), dim3(256), 0, stream>>>(ei, hbuf, linW, linb, out, E);
}

// Round 2
// 1079.933 us; speedup vs baseline: 1.1078x; 1.1078x over previous
//
#include <hip/hip_runtime.h>
#include <stdint.h>
#include <stddef.h>

// Pipeline:
//  k_conv_x : x fp32 -> xbf bf16 [N][256]
//  k_wt     : W [256][1024] -> Wt bf16 [1024][256] (transposed)
//  k_init   : mEnc=-inf enc, denom=0, a_s/a_d/s_row=0, head=-1, pooled=0
//  k_link   : per-dst linked lists over original edges (atomicExch)
//  k_gemm   : xw[N][1024] = x@W via mfma_f32_16x16x32_bf16, store bf16
//             + FUSED epilogue: a_s[n,h]+=<row,att_src>, a_d, s_row (atomicAdd)
//  k_max    : segment max over dst (float-as-uint atomicMax), incl self-loops
//  k_dec    : decode encoded max to float
//  k_denom  : denom[dst,h] += exp(logit - m)
//  k_pool   : pooled[h] = sum_e alpha * s_row[src]   (block-reduced atomics)
//  k_head   : a[h] = softmax(relu(pooled/(N*C)+biasmean)*cw+cb), hb[c]=sum_h a[h]bias
//  k_fuse   : per node (1 wave): h[n,c] = relu(sum_edges sum_h a[h]*alpha*xw[src,h,c] + hb + x)
//  k_out    : per edge (1 wave): out = log_softmax((h[s]*h[d]) @ linW + b)

typedef short bf16x8 __attribute__((ext_vector_type(8)));
typedef float f32x4 __attribute__((ext_vector_type(4)));
typedef unsigned short u16x8 __attribute__((ext_vector_type(8)));
typedef unsigned short u16x4 __attribute__((ext_vector_type(4)));

__device__ __forceinline__ unsigned short f2bf(float f) {
  unsigned u = __float_as_uint(f);
  u += 0x7FFFu + ((u >> 16) & 1u);
  return (unsigned short)(u >> 16);
}
__device__ __forceinline__ float bf2f(unsigned short s) {
  return __uint_as_float(((unsigned)s) << 16);
}
__device__ __forceinline__ unsigned fenc(float f) {
  unsigned b = __float_as_uint(f);
  return (b & 0x80000000u) ? ~b : (b | 0x80000000u);
}
__device__ __forceinline__ float fdec(unsigned u) {
  unsigned b = (u & 0x80000000u) ? (u & 0x7FFFFFFFu) : ~u;
  return __uint_as_float(b);
}
__device__ __forceinline__ float lrelu(float v) { return v >= 0.f ? v : 0.2f * v; }

__device__ __forceinline__ void gload16(const void* g, void* l) {
  __builtin_amdgcn_global_load_lds((const __attribute__((address_space(1))) void*)g,
                                   (__attribute__((address_space(3))) void*)l, 16, 0, 0);
}

// ---------------- conversion kernels ----------------
__global__ __launch_bounds__(256) void k_conv_x(const float* __restrict__ x,
                                                unsigned short* __restrict__ xbf, int total8) {
  int i = blockIdx.x * 256 + threadIdx.x;
  if (i >= total8) return;
  const float4* xp = (const float4*)x;
  float4 a = xp[2 * (size_t)i], b = xp[2 * (size_t)i + 1];
  u16x8 o;
  o[0] = f2bf(a.x); o[1] = f2bf(a.y); o[2] = f2bf(a.z); o[3] = f2bf(a.w);
  o[4] = f2bf(b.x); o[5] = f2bf(b.y); o[6] = f2bf(b.z); o[7] = f2bf(b.w);
  *(u16x8*)(xbf + (size_t)i * 8) = o;
}

__global__ __launch_bounds__(256) void k_wt(const float* __restrict__ W,
                                            unsigned short* __restrict__ wt) {
  int m = blockIdx.x * 256 + threadIdx.x;  // 0..1023
  for (int k = 0; k < 256; ++k) wt[(size_t)m * 256 + k] = f2bf(W[(size_t)k * 1024 + m]);
}

// ---------------- init + edge lists ----------------
__global__ __launch_bounds__(256) void k_init(unsigned* __restrict__ mEnc, float* __restrict__ denom,
                                              float* __restrict__ a_s, float* __restrict__ a_d,
                                              float* __restrict__ s_row,
                                              int* __restrict__ head, float* __restrict__ pooled, int n) {
  int i = blockIdx.x * 256 + threadIdx.x;
  if (i < n * 4) {
    mEnc[i] = 0x007FFFFFu;
    denom[i] = 0.f;
    a_s[i] = 0.f;
    a_d[i] = 0.f;
    s_row[i] = 0.f;
  }
  if (i < n) head[i] = -1;
  if (i < 4) pooled[i] = 0.f;
}

__global__ __launch_bounds__(256) void k_link(const int* __restrict__ ei, int* __restrict__ head,
                                              int* __restrict__ nxt, int E) {
  int e = blockIdx.x * 256 + threadIdx.x;
  if (e >= E) return;
  int dst = ei[E + e];
  nxt[e] = atomicExch(&head[dst], e);
}

// ---------------- GEMM: xw = x @ W (bf16 MFMA 16x16x32) + fused attn dots ----------------
__global__ __launch_bounds__(256) void k_gemm(const unsigned short* __restrict__ A,   // [NR][256] bf16
                                              const unsigned short* __restrict__ Bt,  // [1024][256] bf16 (W^T)
                                              const float* __restrict__ att_s_g,      // [1024]
                                              const float* __restrict__ att_d_g,      // [1024]
                                              unsigned short* __restrict__ C,         // [NR][1024] bf16
                                              float* __restrict__ a_s, float* __restrict__ a_d,
                                              float* __restrict__ s_row,
                                              int NR) {
  __shared__ unsigned short sm[8192];  // As[128][32] + Bs[128][32], 16KB
  unsigned short* As = sm;
  unsigned short* Bs = sm + 4096;
  const int t = threadIdx.x;
  const int w = t >> 6, lane = t & 63;
  const int wm = w >> 1, wn = w & 1;
  const int m0 = blockIdx.x * 128;
  const int n0 = blockIdx.y * 128;

  f32x4 acc[4][4];
#pragma unroll
  for (int i = 0; i < 4; ++i)
#pragma unroll
    for (int j = 0; j < 4; ++j) acc[i][j] = (f32x4){0.f, 0.f, 0.f, 0.f};

  // staging geometry: per wave two 1KB chunks per matrix; HW puts lane l at base+16*l
  const int rQ = lane >> 2;  // row within 16-row chunk
  const int cQ = lane & 3;   // 16B chunk within 64B row
  const int rA0 = (w * 2 + 0) * 16 + rQ;
  const int rA1 = (w * 2 + 1) * 16 + rQ;
  const int scA0 = cQ ^ (rA0 & 3);   // source-side XOR swizzle (read applies same XOR)
  const int scA1 = cQ ^ (rA1 & 3);
  const int gA0 = min(m0 + rA0, NR - 1);
  const int gA1 = min(m0 + rA1, NR - 1);
  const int gB0 = n0 + rA0;
  const int gB1 = n0 + rA1;

  const int kc = lane >> 4;
  const int rl = lane & 15;

#pragma unroll 1
  for (int kk = 0; kk < 8; ++kk) {
    const int k0 = kk * 32;
    gload16(A + (size_t)gA0 * 256 + k0 + scA0 * 8, &As[(w * 2 + 0) * 512]);
    gload16(A + (size_t)gA1 * 256 + k0 + scA1 * 8, &As[(w * 2 + 1) * 512]);
    gload16(Bt + (size_t)gB0 * 256 + k0 + scA0 * 8, &Bs[(w * 2 + 0) * 512]);
    gload16(Bt + (size_t)gB1 * 256 + k0 + scA1 * 8, &Bs[(w * 2 + 1) * 512]);
    __syncthreads();
    bf16x8 aF[4], bF[4];
#pragma unroll
    for (int mi = 0; mi < 4; ++mi) {
      int row = wm * 64 + mi * 16 + rl;
      aF[mi] = *(const bf16x8*)&As[row * 32 + ((kc * 8) ^ ((row & 3) * 8))];
    }
#pragma unroll
    for (int ni = 0; ni < 4; ++ni) {
      int row = wn * 64 + ni * 16 + rl;
      bF[ni] = *(const bf16x8*)&Bs[row * 32 + ((kc * 8) ^ ((row & 3) * 8))];
    }
#pragma unroll
    for (int mi = 0; mi < 4; ++mi)
#pragma unroll
      for (int ni = 0; ni < 4; ++ni)
        acc[mi][ni] = __builtin_amdgcn_mfma_f32_16x16x32_bf16(aF[mi], bF[ni], acc[mi][ni], 0, 0, 0);
    __syncthreads();
  }

  // ---- C store ----
#pragma unroll
  for (int mi = 0; mi < 4; ++mi)
#pragma unroll
    for (int j = 0; j < 4; ++j) {
      int row = m0 + wm * 64 + mi * 16 + kc * 4 + j;
      if (row < NR) {
#pragma unroll
        for (int ni = 0; ni < 4; ++ni) {
          int col = n0 + wn * 64 + ni * 16 + rl;
          C[(size_t)row * 1024 + col] = f2bf(acc[mi][ni][j]);
        }
      }
    }

  // ---- fused attn-scalar epilogue ----
  // This block's 128 columns all belong to head h = blockIdx.y>>1.
  // Per (mi,j): each thread sums its 4 columns; butterfly over the 16-lane
  // column group (lane>>4 constant => same row) gives the 64-col wave sum;
  // one lane per group atomically adds into a_s/a_d/s_row (4 contributors
  // per (row,head) across {blockIdx.y&1, wn}).
  const int h = blockIdx.y >> 1;
  const int col_base = n0 + wn * 64 + rl;
  float att_sv[4], att_dv[4];
#pragma unroll
  for (int ni = 0; ni < 4; ++ni) {
    att_sv[ni] = att_s_g[col_base + ni * 16];
    att_dv[ni] = att_d_g[col_base + ni * 16];
  }
#pragma unroll
  for (int mi = 0; mi < 4; ++mi) {
#pragma unroll
    for (int j = 0; j < 4; ++j) {
      float ps = 0.f, pd = 0.f, pr = 0.f;
#pragma unroll
      for (int ni = 0; ni < 4; ++ni) {
        float v = acc[mi][ni][j];
        ps += v * att_sv[ni];
        pd += v * att_dv[ni];
        pr += v;
      }
#pragma unroll
      for (int o = 1; o <= 8; o <<= 1) {
        ps += __shfl_xor(ps, o);
        pd += __shfl_xor(pd, o);
        pr += __shfl_xor(pr, o);
      }
      if (rl == mi * 4 + j) {
        int row = m0 + wm * 64 + mi * 16 + kc * 4 + j;
        if (row < NR) {
          atomicAdd(&a_s[(size_t)row * 4 + h], ps);
          atomicAdd(&a_d[(size_t)row * 4 + h], pd);
          atomicAdd(&s_row[(size_t)row * 4 + h], pr);
        }
      }
    }
  }
}

// ---------------- segment max / denom / pooled ----------------
__global__ __launch_bounds__(256) void k_max(const int* __restrict__ ei, const float* __restrict__ a_s,
                                             const float* __restrict__ a_d, unsigned* __restrict__ mEnc,
                                             int E, int n) {
  int e = blockIdx.x * 256 + threadIdx.x;
  int tot = E + n;
  if (e >= tot) return;
  int src = e < E ? ei[e] : (e - E);
  int dst = e < E ? ei[E + e] : (e - E);
  float asv[4], adv[4];
  *(float4*)asv = *(const float4*)(a_s + (size_t)src * 4);
  *(float4*)adv = *(const float4*)(a_d + (size_t)dst * 4);
#pragma unroll
  for (int h = 0; h < 4; ++h) {
    float lg = lrelu(asv[h] + adv[h]);
    atomicMax(&mEnc[(size_t)dst * 4 + h], fenc(lg));
  }
}

__global__ __launch_bounds__(256) void k_dec(const unsigned* __restrict__ mEnc,
                                             float* __restrict__ mFlt, int n4) {
  int i = blockIdx.x * 256 + threadIdx.x;
  if (i < n4) mFlt[i] = fdec(mEnc[i]);
}

__global__ __launch_bounds__(256) void k_denom(const int* __restrict__ ei, const float* __restrict__ a_s,
                                               const float* __restrict__ a_d, const float* __restrict__ mFlt,
                                               float* __restrict__ denom, int E, int n) {
  int e = blockIdx.x * 256 + threadIdx.x;
  int tot = E + n;
  if (e >= tot) return;
  int src = e < E ? ei[e] : (e - E);
  int dst = e < E ? ei[E + e] : (e - E);
  float asv[4], adv[4], mv[4];
  *(float4*)asv = *(const float4*)(a_s + (size_t)src * 4);
  *(float4*)adv = *(const float4*)(a_d + (size_t)dst * 4);
  *(float4*)mv = *(const float4*)(mFlt + (size_t)dst * 4);
#pragma unroll
  for (int h = 0; h < 4; ++h) {
    float p = expf(lrelu(asv[h] + adv[h]) - mv[h]);
    atomicAdd(&denom[(size_t)dst * 4 + h], p);
  }
}

__global__ __launch_bounds__(256) void k_pool(const int* __restrict__ ei, const float* __restrict__ a_s,
                                              const float* __restrict__ a_d, const float* __restrict__ mFlt,
                                              const float* __restrict__ denom, const float* __restrict__ s_row,
                                              float* __restrict__ pooled, int E, int n) {
  int e = blockIdx.x * 256 + threadIdx.x;
  int lane = threadIdx.x & 63;
  int tot = E + n;
  bool valid = e < tot;
  float ph[4] = {0.f, 0.f, 0.f, 0.f};
  if (valid) {
    int src = e < E ? ei[e] : (e - E);
    int dst = e < E ? ei[E + e] : (e - E);
    float asv[4], adv[4], mv[4], dv[4], sv[4];
    *(float4*)asv = *(const float4*)(a_s + (size_t)src * 4);
    *(float4*)adv = *(const float4*)(a_d + (size_t)dst * 4);
    *(float4*)mv = *(const float4*)(mFlt + (size_t)dst * 4);
    *(float4*)dv = *(const float4*)(denom + (size_t)dst * 4);
    *(float4*)sv = *(const float4*)(s_row + (size_t)src * 4);
#pragma unroll
    for (int h = 0; h < 4; ++h) {
      float p = expf(lrelu(asv[h] + adv[h]) - mv[h]);
      ph[h] = p / (dv[h] + 1e-16f) * sv[h];
    }
  }
#pragma unroll
  for (int h = 0; h < 4; ++h) {
#pragma unroll
    for (int o = 32; o >= 1; o >>= 1) ph[h] += __shfl_xor(ph[h], o);
  }
  if (lane == 0) {
#pragma unroll
    for (int h = 0; h < 4; ++h) atomicAdd(&pooled[h], ph[h]);
  }
}

// ---------------- head gate + fused bias ----------------
__global__ __launch_bounds__(256) void k_head(const float* __restrict__ pooled,
                                              const float* __restrict__ gbias,
                                              const float* __restrict__ cw, const float* __restrict__ cb,
                                              float* __restrict__ a4, float* __restrict__ hb, int n) {
  __shared__ float red[4][4];
  __shared__ float aa[4];
  int t = threadIdx.x, w = t >> 6, lane = t & 63;
#pragma unroll
  for (int h = 0; h < 4; ++h) {
    float v = gbias[h * 256 + t];
#pragma unroll
    for (int o = 32; o >= 1; o >>= 1) v += __shfl_xor(v, o);
    if (lane == 0) red[h][w] = v;
  }
  __syncthreads();
  if (t == 0) {
    float q[4], mx = -1e30f;
    for (int h = 0; h < 4; ++h) {
      float bm = (red[h][0] + red[h][1] + red[h][2] + red[h][3]) * (1.f / 256.f);
      float pl = pooled[h] / ((float)n * 256.f) + bm;
      float c = pl * cw[0] + cb[0];
      c = fmaxf(c, 0.f);
      q[h] = c;
      mx = fmaxf(mx, c);
    }
    float sum = 0.f;
    for (int h = 0; h < 4; ++h) { q[h] = expf(q[h] - mx); sum += q[h]; }
    for (int h = 0; h < 4; ++h) { aa[h] = q[h] / sum; a4[h] = aa[h]; }
  }
  __syncthreads();
  float hbv = 0.f;
  for (int h = 0; h < 4; ++h) hbv += aa[h] * gbias[h * 256 + t];
  hb[t] = hbv;
}

// ---------------- per-node fused aggregation -> h ----------------
__global__ __launch_bounds__(256) void k_fuse(const int* __restrict__ ei,
                                              const unsigned short* __restrict__ xwbf,
                                              const float* __restrict__ a_s, const float* __restrict__ a_d,
                                              const float* __restrict__ mFlt, const float* __restrict__ denom,
                                              const int* __restrict__ head, const int* __restrict__ nxt,
                                              const float* __restrict__ a4, const float* __restrict__ hb,
                                              const float* __restrict__ x, float* __restrict__ hbuf, int n) {
  int node = blockIdx.x * 4 + (threadIdx.x >> 6);
  int lane = threadIdx.x & 63;
  if (node >= n) return;
  float adv[4], mv[4], dv[4], av[4];
  *(float4*)adv = *(const float4*)(a_d + (size_t)node * 4);
  *(float4*)mv = *(const float4*)(mFlt + (size_t)node * 4);
  *(float4*)dv = *(const float4*)(denom + (size_t)node * 4);
  *(float4*)av = *(const float4*)a4;
  float acc0 = 0.f, acc1 = 0.f, acc2 = 0.f, acc3 = 0.f;
  const int c0 = lane * 4;
  int j = node;  // self-loop first
  int e = -2;
  while (true) {
    float asv[4];
    *(float4*)asv = *(const float4*)(a_s + (size_t)j * 4);
    float ws[4];
#pragma unroll
    for (int h = 0; h < 4; ++h) {
      float p = expf(lrelu(asv[h] + adv[h]) - mv[h]);
      ws[h] = av[h] * p / (dv[h] + 1e-16f);
    }
    const unsigned short* rp = xwbf + (size_t)j * 1024;
#pragma unroll
    for (int h = 0; h < 4; ++h) {
      u16x4 q = *(const u16x4*)(rp + h * 256 + c0);
      acc0 += ws[h] * bf2f(q[0]);
      acc1 += ws[h] * bf2f(q[1]);
      acc2 += ws[h] * bf2f(q[2]);
      acc3 += ws[h] * bf2f(q[3]);
    }
    e = (e == -2) ? head[node] : nxt[e];
    if (e < 0) break;
    j = ei[e];
  }
  float4 xb = *(const float4*)(x + (size_t)node * 256 + c0);
  float4 hbv = *(const float4*)(hb + c0);
  float4 o;
  o.x = fmaxf(acc0 + hbv.x + xb.x, 0.f);
  o.y = fmaxf(acc1 + hbv.y + xb.y, 0.f);
  o.z = fmaxf(acc2 + hbv.z + xb.z, 0.f);
  o.w = fmaxf(acc3 + hbv.w + xb.w, 0.f);
  *(float4*)(hbuf + (size_t)node * 256 + c0) = o;
}

// ---------------- edge classifier + log_softmax ----------------
__global__ __launch_bounds__(256) void k_out(const int* __restrict__ ei, const float* __restrict__ hbuf,
                                             const float* __restrict__ linW, const float* __restrict__ linb,
                                             float* __restrict__ out, int E) {
  int gw = blockIdx.x * 4 + (threadIdx.x >> 6);
  int lane = threadIdx.x & 63;
  if (gw >= E) return;
  int src = ei[gw], dst = ei[E + gw];
  const int c0 = lane * 4;
  float4 hs = *(const float4*)(hbuf + (size_t)src * 256 + c0);
  float4 hd = *(const float4*)(hbuf + (size_t)dst * 256 + c0);
  float4 wa = *(const float4*)(linW + (size_t)c0 * 2);       // (c0,0),(c0,1),(c0+1,0),(c0+1,1)
  float4 wb = *(const float4*)(linW + (size_t)c0 * 2 + 4);   // (c0+2,0),(c0+2,1),(c0+3,0),(c0+3,1)
  float e0 = hs.x * hd.x, e1 = hs.y * hd.y, e2 = hs.z * hd.z, e3 = hs.w * hd.w;
  float u0 = e0 * wa.x + e1 * wa.z + e2 * wb.x + e3 * wb.z;
  float u1 = e0 * wa.y + e1 * wa.w + e2 * wb.y + e3 * wb.w;
#pragma unroll
  for (int o = 32; o >= 1; o >>= 1) {
    u0 += __shfl_xor(u0, o);
    u1 += __shfl_xor(u1, o);
  }
  if (lane == 0) {
    u0 += linb[0];
    u1 += linb[1];
    float mx = fmaxf(u0, u1);
    float lse = mx + logf(expf(u0 - mx) + expf(u1 - mx));
    float2 r;
    r.x = u0 - lse;
    r.y = u1 - lse;
    *(float2*)(out + (size_t)gw * 2) = r;
  }
}

// ---------------- launch ----------------
extern "C" void kernel_launch(void* const* d_in, const int* in_sizes, int n_in,
                              void* d_out, int out_size, void* d_ws, size_t ws_size,
                              hipStream_t stream) {
  const float* x = (const float*)d_in[0];
  const int* ei = (const int*)d_in[1];
  const float* W = (const float*)d_in[2];
  const float* att_s_g = (const float*)d_in[3];
  const float* att_d_g = (const float*)d_in[4];
  const float* gbias = (const float*)d_in[5];
  const float* cw = (const float*)d_in[6];
  const float* cb = (const float*)d_in[7];
  const float* linW = (const float*)d_in[8];
  const float* linb = (const float*)d_in[9];
  float* out = (float*)d_out;

  const int n = in_sizes[0] / 256;   // 100000
  const int E = in_sizes[1] / 2;     // 300000
  const int tot = E + n;

  char* p = (char*)d_ws;
  auto alloc = [&](size_t bytes) -> char* {
    char* r = p;
    p += (bytes + 255) & ~(size_t)255;
    return r;
  };
  unsigned short* xwbf = (unsigned short*)alloc((size_t)n * 1024 * 2);
  unsigned short* xbf = (unsigned short*)alloc((size_t)n * 256 * 2);
  unsigned short* wtbf = (unsigned short*)alloc((size_t)1024 * 256 * 2);
  float* a_s = (float*)alloc((size_t)n * 4 * 4);
  float* a_d = (float*)alloc((size_t)n * 4 * 4);
  float* s_row = (float*)alloc((size_t)n * 4 * 4);
  unsigned* mEnc = (unsigned*)alloc((size_t)n * 4 * 4);
  float* mFlt = (float*)alloc((size_t)n * 4 * 4);
  float* denom = (float*)alloc((size_t)n * 4 * 4);
  int* head = (int*)alloc((size_t)n * 4);
  int* nxt = (int*)alloc((size_t)E * 4);
  float* pooled = (float*)alloc(256);
  float* a4 = (float*)alloc(256);
  float* hb = (float*)alloc(256 * 4);
  float* hbuf = (float*)alloc((size_t)n * 256 * 4);

  int total8 = n * 256 / 8;
  k_conv_x<<<dim3((total8 + 255) / 256), dim3(256), 0, stream>>>(x, xbf, total8);
  k_wt<<<dim3(4), dim3(256), 0, stream>>>(W, wtbf);
  k_init<<<dim3((n * 4 + 255) / 256), dim3(256), 0, stream>>>(mEnc, denom, a_s, a_d, s_row, head, pooled, n);
  k_link<<<dim3((E + 255) / 256), dim3(256), 0, stream>>>(ei, head, nxt, E);
  k_gemm<<<dim3((n + 127) / 128, 8), dim3(256), 0, stream>>>(xbf, wtbf, att_s_g, att_d_g, xwbf, a_s, a_d, s_row, n);
  k_max<<<dim3((tot + 255) / 256), dim3(256), 0, stream>>>(ei, a_s, a_d, mEnc, E, n);
  k_dec<<<dim3((n * 4 + 255) / 256), dim3(256), 0, stream>>>(mEnc, mFlt, n * 4);
  k_denom<<<dim3((tot + 255) / 256), dim3(256), 0, stream>>>(ei, a_s, a_d, mFlt, denom, E, n);
  k_pool<<<dim3((tot + 255) / 256), dim3(256), 0, stream>>>(ei, a_s, a_d, mFlt, denom, s_row, pooled, E, n);
  k_head<<<dim3(1), dim3(256), 0, stream>>>(pooled, gbias, cw, cb, a4, hb, n);
  k_fuse<<<dim3((n + 3) / 4), dim3(256), 0, stream>>>(ei, xwbf, a_s, a_d, mFlt, denom, head, nxt, a4, hb, x, hbuf, n);
  k_out<<<dim3((E + 3) / 4), dim3(256), 0, stream>>>(ei, hbuf, linW, linb, out, E);
}

// Round 3
// 778.866 us; speedup vs baseline: 1.5361x; 1.3865x over previous
//
#include <hip/hip_runtime.h>
#include <stdint.h>
#include <stddef.h>

// Pipeline:
//  k_conv_x : x fp32 -> xbf bf16 [N][256]
//  k_wt     : W [256][1024] -> Wt bf16 [1024][256] (transposed)
//  k_init   : denom=num=a_s=a_d=s_row=0, head=-1, pooled=0
//  k_link   : per-dst linked lists over original edges (atomicExch)
//  k_gemm   : xw[N][1024] = x@W via mfma_f32_16x16x32_bf16, store bf16 via
//             LDS-staged full-line 16B stores (kills write-allocate RMW)
//             + FUSED epilogue: a_s[n,h]+=<row,att_src>, a_d, s_row (atomicAdd)
//  k_denom  : denom[dst,h] += p, num[dst,h] += p*s_row[src,h], p=exp(lrelu(...))
//             (no max-subtraction: logits bounded, softmax shift-invariant)
//  k_pool2  : pooled[h] = sum_dst num/denom  (64-block grid-stride reduce)
//  k_head   : a[h] = softmax(relu(pooled/(N*C)+biasmean)*cw+cb), hb[c]=sum_h a[h]bias
//  k_fuse   : per node (1 wave): h[n,c] = relu(sum_edges sum_h a[h]*alpha*xw[src,h,c] + hb + x)
//  k_out    : per edge (1 wave): out = log_softmax((h[s]*h[d]) @ linW + b)

typedef short bf16x8 __attribute__((ext_vector_type(8)));
typedef float f32x4 __attribute__((ext_vector_type(4)));
typedef unsigned short u16x8 __attribute__((ext_vector_type(8)));
typedef unsigned short u16x4 __attribute__((ext_vector_type(4)));

__device__ __forceinline__ unsigned short f2bf(float f) {
  unsigned u = __float_as_uint(f);
  u += 0x7FFFu + ((u >> 16) & 1u);
  return (unsigned short)(u >> 16);
}
__device__ __forceinline__ float bf2f(unsigned short s) {
  return __uint_as_float(((unsigned)s) << 16);
}
__device__ __forceinline__ float lrelu(float v) { return v >= 0.f ? v : 0.2f * v; }

__device__ __forceinline__ void gload16(const void* g, void* l) {
  __builtin_amdgcn_global_load_lds((const __attribute__((address_space(1))) void*)g,
                                   (__attribute__((address_space(3))) void*)l, 16, 0, 0);
}

// ---------------- conversion kernels ----------------
__global__ __launch_bounds__(256) void k_conv_x(const float* __restrict__ x,
                                                unsigned short* __restrict__ xbf, int total8) {
  int i = blockIdx.x * 256 + threadIdx.x;
  if (i >= total8) return;
  const float4* xp = (const float4*)x;
  float4 a = xp[2 * (size_t)i], b = xp[2 * (size_t)i + 1];
  u16x8 o;
  o[0] = f2bf(a.x); o[1] = f2bf(a.y); o[2] = f2bf(a.z); o[3] = f2bf(a.w);
  o[4] = f2bf(b.x); o[5] = f2bf(b.y); o[6] = f2bf(b.z); o[7] = f2bf(b.w);
  *(u16x8*)(xbf + (size_t)i * 8) = o;
}

__global__ __launch_bounds__(256) void k_wt(const float* __restrict__ W,
                                            unsigned short* __restrict__ wt) {
  int m = blockIdx.x * 256 + threadIdx.x;  // 0..1023
  for (int k = 0; k < 256; ++k) wt[(size_t)m * 256 + k] = f2bf(W[(size_t)k * 1024 + m]);
}

// ---------------- init + edge lists ----------------
__global__ __launch_bounds__(256) void k_init(float* __restrict__ denom, float* __restrict__ num,
                                              float* __restrict__ a_s, float* __restrict__ a_d,
                                              float* __restrict__ s_row,
                                              int* __restrict__ head, float* __restrict__ pooled, int n) {
  int i = blockIdx.x * 256 + threadIdx.x;
  if (i < n * 4) {
    denom[i] = 0.f;
    num[i] = 0.f;
    a_s[i] = 0.f;
    a_d[i] = 0.f;
    s_row[i] = 0.f;
  }
  if (i < n) head[i] = -1;
  if (i < 4) pooled[i] = 0.f;
}

__global__ __launch_bounds__(256) void k_link(const int* __restrict__ ei, int* __restrict__ head,
                                              int* __restrict__ nxt, int E) {
  int e = blockIdx.x * 256 + threadIdx.x;
  if (e >= E) return;
  int dst = ei[E + e];
  nxt[e] = atomicExch(&head[dst], e);
}

// ---------------- GEMM: xw = x @ W (bf16 MFMA 16x16x32) + fused attn dots ----------------
__global__ __launch_bounds__(256) void k_gemm(const unsigned short* __restrict__ A,   // [NR][256] bf16
                                              const unsigned short* __restrict__ Bt,  // [1024][256] bf16 (W^T)
                                              const float* __restrict__ att_s_g,      // [1024]
                                              const float* __restrict__ att_d_g,      // [1024]
                                              unsigned short* __restrict__ C,         // [NR][1024] bf16
                                              float* __restrict__ a_s, float* __restrict__ a_d,
                                              float* __restrict__ s_row,
                                              int NR) {
  // union: K-loop staging (As 8KB + Bs 8KB) / epilogue C-staging (4 waves x 9KB)
  __shared__ unsigned short sm[18432];  // 36 KB
  unsigned short* As = sm;
  unsigned short* Bs = sm + 4096;
  const int t = threadIdx.x;
  const int w = t >> 6, lane = t & 63;
  const int wm = w >> 1, wn = w & 1;
  const int n0 = blockIdx.x * 128;  // 8 col-tiles (x fastest: Bt panel L2-hot)
  const int m0 = blockIdx.y * 128;

  f32x4 acc[4][4];
#pragma unroll
  for (int i = 0; i < 4; ++i)
#pragma unroll
    for (int j = 0; j < 4; ++j) acc[i][j] = (f32x4){0.f, 0.f, 0.f, 0.f};

  // staging geometry: per wave two 1KB chunks per matrix; HW puts lane l at base+16*l
  const int rQ = lane >> 2;  // row within 16-row chunk
  const int cQ = lane & 3;   // 16B chunk within 64B row
  const int rA0 = (w * 2 + 0) * 16 + rQ;
  const int rA1 = (w * 2 + 1) * 16 + rQ;
  const int scA0 = cQ ^ (rA0 & 3);   // source-side XOR swizzle (read applies same XOR)
  const int scA1 = cQ ^ (rA1 & 3);
  const int gA0 = min(m0 + rA0, NR - 1);
  const int gA1 = min(m0 + rA1, NR - 1);
  const int gB0 = n0 + rA0;
  const int gB1 = n0 + rA1;

  const int kc = lane >> 4;
  const int rl = lane & 15;

#pragma unroll 1
  for (int kk = 0; kk < 8; ++kk) {
    const int k0 = kk * 32;
    gload16(A + (size_t)gA0 * 256 + k0 + scA0 * 8, &As[(w * 2 + 0) * 512]);
    gload16(A + (size_t)gA1 * 256 + k0 + scA1 * 8, &As[(w * 2 + 1) * 512]);
    gload16(Bt + (size_t)gB0 * 256 + k0 + scA0 * 8, &Bs[(w * 2 + 0) * 512]);
    gload16(Bt + (size_t)gB1 * 256 + k0 + scA1 * 8, &Bs[(w * 2 + 1) * 512]);
    __syncthreads();
    bf16x8 aF[4], bF[4];
#pragma unroll
    for (int mi = 0; mi < 4; ++mi) {
      int row = wm * 64 + mi * 16 + rl;
      aF[mi] = *(const bf16x8*)&As[row * 32 + ((kc * 8) ^ ((row & 3) * 8))];
    }
#pragma unroll
    for (int ni = 0; ni < 4; ++ni) {
      int row = wn * 64 + ni * 16 + rl;
      bF[ni] = *(const bf16x8*)&Bs[row * 32 + ((kc * 8) ^ ((row & 3) * 8))];
    }
#pragma unroll
    for (int mi = 0; mi < 4; ++mi)
#pragma unroll
      for (int ni = 0; ni < 4; ++ni)
        acc[mi][ni] = __builtin_amdgcn_mfma_f32_16x16x32_bf16(aF[mi], bF[ni], acc[mi][ni], 0, 0, 0);
    __syncthreads();
  }

  // ---- C store via LDS staging: full-line 16B coalesced stores ----
  // per-wave region: 64 rows x 72 shorts (pad 8 -> 144B stride, 2-way-free writes)
  {
    unsigned short* St = sm + w * 4608;
#pragma unroll
    for (int mi = 0; mi < 4; ++mi)
#pragma unroll
      for (int ni = 0; ni < 4; ++ni)
#pragma unroll
        for (int j = 0; j < 4; ++j)
          St[(mi * 16 + kc * 4 + j) * 72 + ni * 16 + rl] = f2bf(acc[mi][ni][j]);
    // same-wave write->read dependency: compiler inserts lgkmcnt
#pragma unroll
    for (int it = 0; it < 8; ++it) {
      int idx = it * 64 + lane;
      int row = idx >> 3;   // 0..63
      int ch = idx & 7;     // 16B chunk within 128B row
      u16x8 v = *(const u16x8*)&St[row * 72 + ch * 8];
      int grow = m0 + wm * 64 + row;
      if (grow < NR)
        *(u16x8*)&C[(size_t)grow * 1024 + n0 + wn * 64 + ch * 8] = v;
    }
  }

  // ---- fused attn-scalar epilogue ----
  // This block's 128 columns all belong to head h = blockIdx.x>>1.
  const int h = blockIdx.x >> 1;
  const int col_base = n0 + wn * 64 + rl;
  float att_sv[4], att_dv[4];
#pragma unroll
  for (int ni = 0; ni < 4; ++ni) {
    att_sv[ni] = att_s_g[col_base + ni * 16];
    att_dv[ni] = att_d_g[col_base + ni * 16];
  }
#pragma unroll
  for (int mi = 0; mi < 4; ++mi) {
#pragma unroll
    for (int j = 0; j < 4; ++j) {
      float ps = 0.f, pd = 0.f, pr = 0.f;
#pragma unroll
      for (int ni = 0; ni < 4; ++ni) {
        float v = acc[mi][ni][j];
        ps += v * att_sv[ni];
        pd += v * att_dv[ni];
        pr += v;
      }
#pragma unroll
      for (int o = 1; o <= 8; o <<= 1) {
        ps += __shfl_xor(ps, o);
        pd += __shfl_xor(pd, o);
        pr += __shfl_xor(pr, o);
      }
      if (rl == mi * 4 + j) {
        int row = m0 + wm * 64 + mi * 16 + kc * 4 + j;
        if (row < NR) {
          atomicAdd(&a_s[(size_t)row * 4 + h], ps);
          atomicAdd(&a_d[(size_t)row * 4 + h], pd);
          atomicAdd(&s_row[(size_t)row * 4 + h], pr);
        }
      }
    }
  }
}

// ---------------- per-edge denom + numerator (incl self-loops) ----------------
__global__ __launch_bounds__(256) void k_denom(const int* __restrict__ ei, const float* __restrict__ a_s,
                                               const float* __restrict__ a_d, const float* __restrict__ s_row,
                                               float* __restrict__ denom, float* __restrict__ num,
                                               int E, int n) {
  int e = blockIdx.x * 256 + threadIdx.x;
  int tot = E + n;
  if (e >= tot) return;
  int src = e < E ? ei[e] : (e - E);
  int dst = e < E ? ei[E + e] : (e - E);
  float asv[4], adv[4], sv[4];
  *(float4*)asv = *(const float4*)(a_s + (size_t)src * 4);
  *(float4*)adv = *(const float4*)(a_d + (size_t)dst * 4);
  *(float4*)sv = *(const float4*)(s_row + (size_t)src * 4);
#pragma unroll
  for (int h = 0; h < 4; ++h) {
    float p = expf(lrelu(asv[h] + adv[h]));
    atomicAdd(&denom[(size_t)dst * 4 + h], p);
    atomicAdd(&num[(size_t)dst * 4 + h], p * sv[h]);
  }
}

// ---------------- pooled[h] = sum_dst num/denom ----------------
__global__ __launch_bounds__(256) void k_pool2(const float* __restrict__ denom,
                                               const float* __restrict__ num,
                                               float* __restrict__ pooled, int n) {
  float ph[4] = {0.f, 0.f, 0.f, 0.f};
  for (int i = blockIdx.x * 256 + threadIdx.x; i < n; i += gridDim.x * 256) {
    float4 dv = *(const float4*)(denom + (size_t)i * 4);
    float4 nv = *(const float4*)(num + (size_t)i * 4);
    ph[0] += nv.x / (dv.x + 1e-16f);
    ph[1] += nv.y / (dv.y + 1e-16f);
    ph[2] += nv.z / (dv.z + 1e-16f);
    ph[3] += nv.w / (dv.w + 1e-16f);
  }
  int w = threadIdx.x >> 6, lane = threadIdx.x & 63;
#pragma unroll
  for (int h = 0; h < 4; ++h)
#pragma unroll
    for (int o = 32; o >= 1; o >>= 1) ph[h] += __shfl_xor(ph[h], o);
  __shared__ float red[4][4];
  if (lane == 0) {
#pragma unroll
    for (int h = 0; h < 4; ++h) red[w][h] = ph[h];
  }
  __syncthreads();
  if (threadIdx.x == 0) {
#pragma unroll
    for (int h = 0; h < 4; ++h)
      atomicAdd(&pooled[h], red[0][h] + red[1][h] + red[2][h] + red[3][h]);
  }
}

// ---------------- head gate + fused bias ----------------
__global__ __launch_bounds__(256) void k_head(const float* __restrict__ pooled,
                                              const float* __restrict__ gbias,
                                              const float* __restrict__ cw, const float* __restrict__ cb,
                                              float* __restrict__ a4, float* __restrict__ hb, int n) {
  __shared__ float red[4][4];
  __shared__ float aa[4];
  int t = threadIdx.x, w = t >> 6, lane = t & 63;
#pragma unroll
  for (int h = 0; h < 4; ++h) {
    float v = gbias[h * 256 + t];
#pragma unroll
    for (int o = 32; o >= 1; o >>= 1) v += __shfl_xor(v, o);
    if (lane == 0) red[h][w] = v;
  }
  __syncthreads();
  if (t == 0) {
    float q[4], mx = -1e30f;
    for (int h = 0; h < 4; ++h) {
      float bm = (red[h][0] + red[h][1] + red[h][2] + red[h][3]) * (1.f / 256.f);
      float pl = pooled[h] / ((float)n * 256.f) + bm;
      float c = pl * cw[0] + cb[0];
      c = fmaxf(c, 0.f);
      q[h] = c;
      mx = fmaxf(mx, c);
    }
    float sum = 0.f;
    for (int h = 0; h < 4; ++h) { q[h] = expf(q[h] - mx); sum += q[h]; }
    for (int h = 0; h < 4; ++h) { aa[h] = q[h] / sum; a4[h] = aa[h]; }
  }
  __syncthreads();
  float hbv = 0.f;
  for (int h = 0; h < 4; ++h) hbv += aa[h] * gbias[h * 256 + t];
  hb[t] = hbv;
}

// ---------------- per-node fused aggregation -> h ----------------
__global__ __launch_bounds__(256) void k_fuse(const int* __restrict__ ei,
                                              const unsigned short* __restrict__ xwbf,
                                              const float* __restrict__ a_s, const float* __restrict__ a_d,
                                              const float* __restrict__ denom,
                                              const int* __restrict__ head, const int* __restrict__ nxt,
                                              const float* __restrict__ a4, const float* __restrict__ hb,
                                              const float* __restrict__ x, float* __restrict__ hbuf, int n) {
  int node = blockIdx.x * 4 + (threadIdx.x >> 6);
  int lane = threadIdx.x & 63;
  if (node >= n) return;
  float adv[4], dv[4], av[4];
  *(float4*)adv = *(const float4*)(a_d + (size_t)node * 4);
  *(float4*)dv = *(const float4*)(denom + (size_t)node * 4);
  *(float4*)av = *(const float4*)a4;
  float acc0 = 0.f, acc1 = 0.f, acc2 = 0.f, acc3 = 0.f;
  const int c0 = lane * 4;
  int j = node;  // self-loop first
  int e = -2;
  while (true) {
    float asv[4];
    *(float4*)asv = *(const float4*)(a_s + (size_t)j * 4);
    float ws[4];
#pragma unroll
    for (int h = 0; h < 4; ++h) {
      float p = expf(lrelu(asv[h] + adv[h]));
      ws[h] = av[h] * p / (dv[h] + 1e-16f);
    }
    const unsigned short* rp = xwbf + (size_t)j * 1024;
#pragma unroll
    for (int h = 0; h < 4; ++h) {
      u16x4 q = *(const u16x4*)(rp + h * 256 + c0);
      acc0 += ws[h] * bf2f(q[0]);
      acc1 += ws[h] * bf2f(q[1]);
      acc2 += ws[h] * bf2f(q[2]);
      acc3 += ws[h] * bf2f(q[3]);
    }
    e = (e == -2) ? head[node] : nxt[e];
    if (e < 0) break;
    j = ei[e];
  }
  float4 xb = *(const float4*)(x + (size_t)node * 256 + c0);
  float4 hbv = *(const float4*)(hb + c0);
  float4 o;
  o.x = fmaxf(acc0 + hbv.x + xb.x, 0.f);
  o.y = fmaxf(acc1 + hbv.y + xb.y, 0.f);
  o.z = fmaxf(acc2 + hbv.z + xb.z, 0.f);
  o.w = fmaxf(acc3 + hbv.w + xb.w, 0.f);
  *(float4*)(hbuf + (size_t)node * 256 + c0) = o;
}

// ---------------- edge classifier + log_softmax ----------------
__global__ __launch_bounds__(256) void k_out(const int* __restrict__ ei, const float* __restrict__ hbuf,
                                             const float* __restrict__ linW, const float* __restrict__ linb,
                                             float* __restrict__ out, int E) {
  int gw = blockIdx.x * 4 + (threadIdx.x >> 6);
  int lane = threadIdx.x & 63;
  if (gw >= E) return;
  int src = ei[gw], dst = ei[E + gw];
  const int c0 = lane * 4;
  float4 hs = *(const float4*)(hbuf + (size_t)src * 256 + c0);
  float4 hd = *(const float4*)(hbuf + (size_t)dst * 256 + c0);
  float4 wa = *(const float4*)(linW + (size_t)c0 * 2);       // (c0,0),(c0,1),(c0+1,0),(c0+1,1)
  float4 wb = *(const float4*)(linW + (size_t)c0 * 2 + 4);   // (c0+2,0),(c0+2,1),(c0+3,0),(c0+3,1)
  float e0 = hs.x * hd.x, e1 = hs.y * hd.y, e2 = hs.z * hd.z, e3 = hs.w * hd.w;
  float u0 = e0 * wa.x + e1 * wa.z + e2 * wb.x + e3 * wb.z;
  float u1 = e0 * wa.y + e1 * wa.w + e2 * wb.y + e3 * wb.w;
#pragma unroll
  for (int o = 32; o >= 1; o >>= 1) {
    u0 += __shfl_xor(u0, o);
    u1 += __shfl_xor(u1, o);
  }
  if (lane == 0) {
    u0 += linb[0];
    u1 += linb[1];
    float mx = fmaxf(u0, u1);
    float lse = mx + logf(expf(u0 - mx) + expf(u1 - mx));
    float2 r;
    r.x = u0 - lse;
    r.y = u1 - lse;
    *(float2*)(out + (size_t)gw * 2) = r;
  }
}

// ---------------- launch ----------------
extern "C" void kernel_launch(void* const* d_in, const int* in_sizes, int n_in,
                              void* d_out, int out_size, void* d_ws, size_t ws_size,
                              hipStream_t stream) {
  const float* x = (const float*)d_in[0];
  const int* ei = (const int*)d_in[1];
  const float* W = (const float*)d_in[2];
  const float* att_s_g = (const float*)d_in[3];
  const float* att_d_g = (const float*)d_in[4];
  const float* gbias = (const float*)d_in[5];
  const float* cw = (const float*)d_in[6];
  const float* cb = (const float*)d_in[7];
  const float* linW = (const float*)d_in[8];
  const float* linb = (const float*)d_in[9];
  float* out = (float*)d_out;

  const int n = in_sizes[0] / 256;   // 100000
  const int E = in_sizes[1] / 2;     // 300000
  const int tot = E + n;

  char* p = (char*)d_ws;
  auto alloc = [&](size_t bytes) -> char* {
    char* r = p;
    p += (bytes + 255) & ~(size_t)255;
    return r;
  };
  unsigned short* xwbf = (unsigned short*)alloc((size_t)n * 1024 * 2);
  unsigned short* xbf = (unsigned short*)alloc((size_t)n * 256 * 2);
  unsigned short* wtbf = (unsigned short*)alloc((size_t)1024 * 256 * 2);
  float* a_s = (float*)alloc((size_t)n * 4 * 4);
  float* a_d = (float*)alloc((size_t)n * 4 * 4);
  float* s_row = (float*)alloc((size_t)n * 4 * 4);
  float* denom = (float*)alloc((size_t)n * 4 * 4);
  float* num = (float*)alloc((size_t)n * 4 * 4);
  int* head = (int*)alloc((size_t)n * 4);
  int* nxt = (int*)alloc((size_t)E * 4);
  float* pooled = (float*)alloc(256);
  float* a4 = (float*)alloc(256);
  float* hb = (float*)alloc(256 * 4);
  float* hbuf = (float*)alloc((size_t)n * 256 * 4);

  int total8 = n * 256 / 8;
  k_conv_x<<<dim3((total8 + 255) / 256), dim3(256), 0, stream>>>(x, xbf, total8);
  k_wt<<<dim3(4), dim3(256), 0, stream>>>(W, wtbf);
  k_init<<<dim3((n * 4 + 255) / 256), dim3(256), 0, stream>>>(denom, num, a_s, a_d, s_row, head, pooled, n);
  k_link<<<dim3((E + 255) / 256), dim3(256), 0, stream>>>(ei, head, nxt, E);
  k_gemm<<<dim3(8, (n + 127) / 128), dim3(256), 0, stream>>>(xbf, wtbf, att_s_g, att_d_g, xwbf, a_s, a_d, s_row, n);
  k_denom<<<dim3((tot + 255) / 256), dim3(256), 0, stream>>>(ei, a_s, a_d, s_row, denom, num, E, n);
  k_pool2<<<dim3(64), dim3(256), 0, stream>>>(denom, num, pooled, n);
  k_head<<<dim3(1), dim3(256), 0, stream>>>(pooled, gbias, cw, cb, a4, hb, n);
  k_fuse<<<dim3((n + 3) / 4), dim3(256), 0, stream>>>(ei, xwbf, a_s, a_d, denom, head, nxt, a4, hb, x, hbuf, n);
  k_out<<<dim3((E + 3) / 4), dim3(256), 0, stream>>>(ei, hbuf, linW, linb, out, E);
}

// Round 4
// 666.150 us; speedup vs baseline: 1.7960x; 1.1692x over previous
//
#include <hip/hip_runtime.h>
#include <stdint.h>
#include <stddef.h>

// Pipeline:
//  k_conv_x : x fp32 -> xbf bf16 [N][256]
//  k_wt     : W [256][1024] -> Wt bf16 [1024][256] (transposed)
//  k_init   : denom=num=0, head=-1, pooled=0
//  k_link   : per-dst linked lists over original edges (atomicExch)
//  k_gemm   : full-N-per-block: 128 rows x 1024 cols. A panel staged to LDS once
//             (64KB, XOR-swizzled via pre-swizzled global src); Bt 64-col strips
//             double-buffered (2x32KB). Barrier-free 8-step K-loop per strip.
//             a_s/a_d/s_row computed block-locally -> plain stores, NO atomics.
//  k_denom  : denom[dst,h] += p, num[dst,h] += p*s_row[src,h], p=exp(lrelu(...))
//  k_pool2  : pooled[h] = sum_dst num/denom  (64-block grid-stride reduce)
//  k_head   : a[h] = softmax(relu(pooled/(N*C)+biasmean)*cw+cb), hb[c]=sum_h a[h]bias
//  k_fuse   : per node (1 wave): h[n,c] = relu(sum_edges sum_h a[h]*alpha*xw[src,h,c] + hb + x)
//  k_out    : per edge (1 wave): out = log_softmax((h[s]*h[d]) @ linW + b)

typedef short bf16x8 __attribute__((ext_vector_type(8)));
typedef float f32x4 __attribute__((ext_vector_type(4)));
typedef unsigned short u16x8 __attribute__((ext_vector_type(8)));
typedef unsigned short u16x4 __attribute__((ext_vector_type(4)));

__device__ __forceinline__ unsigned short f2bf(float f) {
  unsigned u = __float_as_uint(f);
  u += 0x7FFFu + ((u >> 16) & 1u);
  return (unsigned short)(u >> 16);
}
__device__ __forceinline__ float bf2f(unsigned short s) {
  return __uint_as_float(((unsigned)s) << 16);
}
__device__ __forceinline__ float lrelu(float v) { return v >= 0.f ? v : 0.2f * v; }

__device__ __forceinline__ void gload16(const void* g, void* l) {
  __builtin_amdgcn_global_load_lds((const __attribute__((address_space(1))) void*)g,
                                   (__attribute__((address_space(3))) void*)l, 16, 0, 0);
}

// ---------------- conversion kernels ----------------
__global__ __launch_bounds__(256) void k_conv_x(const float* __restrict__ x,
                                                unsigned short* __restrict__ xbf, int total8) {
  int i = blockIdx.x * 256 + threadIdx.x;
  if (i >= total8) return;
  const float4* xp = (const float4*)x;
  float4 a = xp[2 * (size_t)i], b = xp[2 * (size_t)i + 1];
  u16x8 o;
  o[0] = f2bf(a.x); o[1] = f2bf(a.y); o[2] = f2bf(a.z); o[3] = f2bf(a.w);
  o[4] = f2bf(b.x); o[5] = f2bf(b.y); o[6] = f2bf(b.z); o[7] = f2bf(b.w);
  *(u16x8*)(xbf + (size_t)i * 8) = o;
}

__global__ __launch_bounds__(256) void k_wt(const float* __restrict__ W,
                                            unsigned short* __restrict__ wt) {
  int m = blockIdx.x * 256 + threadIdx.x;  // 0..1023
  for (int k = 0; k < 256; ++k) wt[(size_t)m * 256 + k] = f2bf(W[(size_t)k * 1024 + m]);
}

// ---------------- init + edge lists ----------------
__global__ __launch_bounds__(256) void k_init(float* __restrict__ denom, float* __restrict__ num,
                                              int* __restrict__ head, float* __restrict__ pooled, int n) {
  int i = blockIdx.x * 256 + threadIdx.x;
  if (i < n * 4) {
    denom[i] = 0.f;
    num[i] = 0.f;
  }
  if (i < n) head[i] = -1;
  if (i < 4) pooled[i] = 0.f;
}

__global__ __launch_bounds__(256) void k_link(const int* __restrict__ ei, int* __restrict__ head,
                                              int* __restrict__ nxt, int E) {
  int e = blockIdx.x * 256 + threadIdx.x;
  if (e >= E) return;
  int dst = ei[E + e];
  nxt[e] = atomicExch(&head[dst], e);
}

// ---------------- GEMM: xw = x @ W, full-N per block ----------------
// block: 128 rows x 1024 cols; 4 waves, wave w owns rows [w*32, w*32+32).
// A[128][256] in LDS once; Bt strips of 64 cols double-buffered.
// LDS layout (both): [row][chunk16B c], data = global[row][c ^ (row&7)];
// frag read applies the same XOR -> ds_read_b128 2-way (free).
__global__ __launch_bounds__(256) void k_gemm(const unsigned short* __restrict__ A,   // [NR][256] bf16
                                              const unsigned short* __restrict__ Bt,  // [1024][256] bf16 (W^T)
                                              const float* __restrict__ att_s_g,      // [1024]
                                              const float* __restrict__ att_d_g,      // [1024]
                                              unsigned short* __restrict__ C,         // [NR][1024] bf16
                                              float* __restrict__ a_s, float* __restrict__ a_d,
                                              float* __restrict__ s_row,
                                              int NR) {
  __shared__ unsigned short As[128 * 256];    // 64 KB
  __shared__ unsigned short Bs[2][64 * 256];  // 2 x 32 KB
  const int t = threadIdx.x;
  const int w = t >> 6, lane = t & 63;
  const int kc = lane >> 4, rl = lane & 15;
  const int m0 = blockIdx.x * 128;

  // ---- stage A panel (pre-swizzled source, linear LDS dest) ----
#pragma unroll
  for (int i = 0; i < 16; ++i) {
    int idx = i * 256 + t;          // == i*256 + w*64 + lane
    int r = idx >> 5, c = idx & 31;
    int gr = min(m0 + r, NR - 1);
    gload16(A + (size_t)gr * 256 + ((c ^ (r & 7)) << 3), &As[(i * 256 + w * 64) * 8]);
  }
  // ---- stage B strip 0 ----
#pragma unroll
  for (int i = 0; i < 8; ++i) {
    int idx = i * 256 + t;
    int br = idx >> 5, c = idx & 31;
    gload16(Bt + (size_t)br * 256 + ((c ^ (br & 7)) << 3), &Bs[0][(i * 256 + w * 64) * 8]);
  }
  __syncthreads();

  float as_run[2][4], ad_run[2][4], sr_run[2][4];
#pragma unroll
  for (int mi = 0; mi < 2; ++mi)
#pragma unroll
    for (int j = 0; j < 4; ++j) { as_run[mi][j] = 0.f; ad_run[mi][j] = 0.f; sr_run[mi][j] = 0.f; }

#pragma unroll 1
  for (int hn = 0; hn < 16; ++hn) {
    const int cb0 = hn * 64;
    const int cur = hn & 1;
    // prefetch next strip into other buffer
    if (hn < 15) {
      const int cbn = cb0 + 64;
#pragma unroll
      for (int i = 0; i < 8; ++i) {
        int idx = i * 256 + t;
        int br = idx >> 5, c = idx & 31;
        gload16(Bt + (size_t)(cbn + br) * 256 + ((c ^ (br & 7)) << 3),
                &Bs[cur ^ 1][(i * 256 + w * 64) * 8]);
      }
    }

    f32x4 acc[2][4];
#pragma unroll
    for (int mi = 0; mi < 2; ++mi)
#pragma unroll
      for (int ni = 0; ni < 4; ++ni) acc[mi][ni] = (f32x4){0.f, 0.f, 0.f, 0.f};

#pragma unroll
    for (int kk = 0; kk < 8; ++kk) {
      bf16x8 aF[2], bF[4];
#pragma unroll
      for (int mi = 0; mi < 2; ++mi) {
        int r = w * 32 + mi * 16 + rl;
        aF[mi] = *(const bf16x8*)&As[r * 256 + (((kk * 4 + kc) ^ (r & 7)) << 3)];
      }
#pragma unroll
      for (int ni = 0; ni < 4; ++ni) {
        int br = ni * 16 + rl;
        bF[ni] = *(const bf16x8*)&Bs[cur][br * 256 + (((kk * 4 + kc) ^ (br & 7)) << 3)];
      }
#pragma unroll
      for (int mi = 0; mi < 2; ++mi)
#pragma unroll
        for (int ni = 0; ni < 4; ++ni)
          acc[mi][ni] = __builtin_amdgcn_mfma_f32_16x16x32_bf16(aF[mi], bF[ni], acc[mi][ni], 0, 0, 0);
    }

    // ---- C store + attn partial accumulation (all block-local) ----
    const int h = hn >> 2;
    float asv[4], adv[4];
#pragma unroll
    for (int ni = 0; ni < 4; ++ni) {
      asv[ni] = att_s_g[cb0 + ni * 16 + rl];
      adv[ni] = att_d_g[cb0 + ni * 16 + rl];
    }
#pragma unroll
    for (int mi = 0; mi < 2; ++mi)
#pragma unroll
      for (int j = 0; j < 4; ++j) {
        int row = m0 + w * 32 + mi * 16 + kc * 4 + j;
        bool ok = row < NR;
        float ps = 0.f, pd = 0.f, pr = 0.f;
#pragma unroll
        for (int ni = 0; ni < 4; ++ni) {
          float v = acc[mi][ni][j];
          ps += v * asv[ni];
          pd += v * adv[ni];
          pr += v;
          if (ok) C[(size_t)row * 1024 + cb0 + ni * 16 + rl] = f2bf(v);
        }
        as_run[mi][j] += ps; ad_run[mi][j] += pd; sr_run[mi][j] += pr;
      }
    // head boundary: reduce over the 16-lane column group, store (no atomics)
    if ((hn & 3) == 3) {
#pragma unroll
      for (int mi = 0; mi < 2; ++mi)
#pragma unroll
        for (int j = 0; j < 4; ++j) {
          float ps = as_run[mi][j], pd = ad_run[mi][j], pr = sr_run[mi][j];
#pragma unroll
          for (int o = 1; o <= 8; o <<= 1) {
            ps += __shfl_xor(ps, o);
            pd += __shfl_xor(pd, o);
            pr += __shfl_xor(pr, o);
          }
          if (rl == 0) {
            int row = m0 + w * 32 + mi * 16 + kc * 4 + j;
            if (row < NR) {
              a_s[(size_t)row * 4 + h] = ps;
              a_d[(size_t)row * 4 + h] = pd;
              s_row[(size_t)row * 4 + h] = pr;
            }
          }
          as_run[mi][j] = 0.f; ad_run[mi][j] = 0.f; sr_run[mi][j] = 0.f;
        }
    }
    __syncthreads();
  }
}

// ---------------- per-edge denom + numerator (incl self-loops) ----------------
__global__ __launch_bounds__(256) void k_denom(const int* __restrict__ ei, const float* __restrict__ a_s,
                                               const float* __restrict__ a_d, const float* __restrict__ s_row,
                                               float* __restrict__ denom, float* __restrict__ num,
                                               int E, int n) {
  int e = blockIdx.x * 256 + threadIdx.x;
  int tot = E + n;
  if (e >= tot) return;
  int src = e < E ? ei[e] : (e - E);
  int dst = e < E ? ei[E + e] : (e - E);
  float asv[4], adv[4], sv[4];
  *(float4*)asv = *(const float4*)(a_s + (size_t)src * 4);
  *(float4*)adv = *(const float4*)(a_d + (size_t)dst * 4);
  *(float4*)sv = *(const float4*)(s_row + (size_t)src * 4);
#pragma unroll
  for (int h = 0; h < 4; ++h) {
    float p = expf(lrelu(asv[h] + adv[h]));
    atomicAdd(&denom[(size_t)dst * 4 + h], p);
    atomicAdd(&num[(size_t)dst * 4 + h], p * sv[h]);
  }
}

// ---------------- pooled[h] = sum_dst num/denom ----------------
__global__ __launch_bounds__(256) void k_pool2(const float* __restrict__ denom,
                                               const float* __restrict__ num,
                                               float* __restrict__ pooled, int n) {
  float ph[4] = {0.f, 0.f, 0.f, 0.f};
  for (int i = blockIdx.x * 256 + threadIdx.x; i < n; i += gridDim.x * 256) {
    float4 dv = *(const float4*)(denom + (size_t)i * 4);
    float4 nv = *(const float4*)(num + (size_t)i * 4);
    ph[0] += nv.x / (dv.x + 1e-16f);
    ph[1] += nv.y / (dv.y + 1e-16f);
    ph[2] += nv.z / (dv.z + 1e-16f);
    ph[3] += nv.w / (dv.w + 1e-16f);
  }
  int w = threadIdx.x >> 6, lane = threadIdx.x & 63;
#pragma unroll
  for (int h = 0; h < 4; ++h)
#pragma unroll
    for (int o = 32; o >= 1; o >>= 1) ph[h] += __shfl_xor(ph[h], o);
  __shared__ float red[4][4];
  if (lane == 0) {
#pragma unroll
    for (int h = 0; h < 4; ++h) red[w][h] = ph[h];
  }
  __syncthreads();
  if (threadIdx.x == 0) {
#pragma unroll
    for (int h = 0; h < 4; ++h)
      atomicAdd(&pooled[h], red[0][h] + red[1][h] + red[2][h] + red[3][h]);
  }
}

// ---------------- head gate + fused bias ----------------
__global__ __launch_bounds__(256) void k_head(const float* __restrict__ pooled,
                                              const float* __restrict__ gbias,
                                              const float* __restrict__ cw, const float* __restrict__ cb,
                                              float* __restrict__ a4, float* __restrict__ hb, int n) {
  __shared__ float red[4][4];
  __shared__ float aa[4];
  int t = threadIdx.x, w = t >> 6, lane = t & 63;
#pragma unroll
  for (int h = 0; h < 4; ++h) {
    float v = gbias[h * 256 + t];
#pragma unroll
    for (int o = 32; o >= 1; o >>= 1) v += __shfl_xor(v, o);
    if (lane == 0) red[h][w] = v;
  }
  __syncthreads();
  if (t == 0) {
    float q[4], mx = -1e30f;
    for (int h = 0; h < 4; ++h) {
      float bm = (red[h][0] + red[h][1] + red[h][2] + red[h][3]) * (1.f / 256.f);
      float pl = pooled[h] / ((float)n * 256.f) + bm;
      float c = pl * cw[0] + cb[0];
      c = fmaxf(c, 0.f);
      q[h] = c;
      mx = fmaxf(mx, c);
    }
    float sum = 0.f;
    for (int h = 0; h < 4; ++h) { q[h] = expf(q[h] - mx); sum += q[h]; }
    for (int h = 0; h < 4; ++h) { aa[h] = q[h] / sum; a4[h] = aa[h]; }
  }
  __syncthreads();
  float hbv = 0.f;
  for (int h = 0; h < 4; ++h) hbv += aa[h] * gbias[h * 256 + t];
  hb[t] = hbv;
}

// ---------------- per-node fused aggregation -> h ----------------
__global__ __launch_bounds__(256) void k_fuse(const int* __restrict__ ei,
                                              const unsigned short* __restrict__ xwbf,
                                              const float* __restrict__ a_s, const float* __restrict__ a_d,
                                              const float* __restrict__ denom,
                                              const int* __restrict__ head, const int* __restrict__ nxt,
                                              const float* __restrict__ a4, const float* __restrict__ hb,
                                              const float* __restrict__ x, float* __restrict__ hbuf, int n) {
  int node = blockIdx.x * 4 + (threadIdx.x >> 6);
  int lane = threadIdx.x & 63;
  if (node >= n) return;
  float adv[4], dv[4], av[4];
  *(float4*)adv = *(const float4*)(a_d + (size_t)node * 4);
  *(float4*)dv = *(const float4*)(denom + (size_t)node * 4);
  *(float4*)av = *(const float4*)a4;
  float acc0 = 0.f, acc1 = 0.f, acc2 = 0.f, acc3 = 0.f;
  const int c0 = lane * 4;
  int j = node;  // self-loop first
  int e = -2;
  while (true) {
    float asv[4];
    *(float4*)asv = *(const float4*)(a_s + (size_t)j * 4);
    float ws[4];
#pragma unroll
    for (int h = 0; h < 4; ++h) {
      float p = expf(lrelu(asv[h] + adv[h]));
      ws[h] = av[h] * p / (dv[h] + 1e-16f);
    }
    const unsigned short* rp = xwbf + (size_t)j * 1024;
#pragma unroll
    for (int h = 0; h < 4; ++h) {
      u16x4 q = *(const u16x4*)(rp + h * 256 + c0);
      acc0 += ws[h] * bf2f(q[0]);
      acc1 += ws[h] * bf2f(q[1]);
      acc2 += ws[h] * bf2f(q[2]);
      acc3 += ws[h] * bf2f(q[3]);
    }
    e = (e == -2) ? head[node] : nxt[e];
    if (e < 0) break;
    j = ei[e];
  }
  float4 xb = *(const float4*)(x + (size_t)node * 256 + c0);
  float4 hbv = *(const float4*)(hb + c0);
  float4 o;
  o.x = fmaxf(acc0 + hbv.x + xb.x, 0.f);
  o.y = fmaxf(acc1 + hbv.y + xb.y, 0.f);
  o.z = fmaxf(acc2 + hbv.z + xb.z, 0.f);
  o.w = fmaxf(acc3 + hbv.w + xb.w, 0.f);
  *(float4*)(hbuf + (size_t)node * 256 + c0) = o;
}

// ---------------- edge classifier + log_softmax ----------------
__global__ __launch_bounds__(256) void k_out(const int* __restrict__ ei, const float* __restrict__ hbuf,
                                             const float* __restrict__ linW, const float* __restrict__ linb,
                                             float* __restrict__ out, int E) {
  int gw = blockIdx.x * 4 + (threadIdx.x >> 6);
  int lane = threadIdx.x & 63;
  if (gw >= E) return;
  int src = ei[gw], dst = ei[E + gw];
  const int c0 = lane * 4;
  float4 hs = *(const float4*)(hbuf + (size_t)src * 256 + c0);
  float4 hd = *(const float4*)(hbuf + (size_t)dst * 256 + c0);
  float4 wa = *(const float4*)(linW + (size_t)c0 * 2);       // (c0,0),(c0,1),(c0+1,0),(c0+1,1)
  float4 wb = *(const float4*)(linW + (size_t)c0 * 2 + 4);   // (c0+2,0),(c0+2,1),(c0+3,0),(c0+3,1)
  float e0 = hs.x * hd.x, e1 = hs.y * hd.y, e2 = hs.z * hd.z, e3 = hs.w * hd.w;
  float u0 = e0 * wa.x + e1 * wa.z + e2 * wb.x + e3 * wb.z;
  float u1 = e0 * wa.y + e1 * wa.w + e2 * wb.y + e3 * wb.w;
#pragma unroll
  for (int o = 32; o >= 1; o >>= 1) {
    u0 += __shfl_xor(u0, o);
    u1 += __shfl_xor(u1, o);
  }
  if (lane == 0) {
    u0 += linb[0];
    u1 += linb[1];
    float mx = fmaxf(u0, u1);
    float lse = mx + logf(expf(u0 - mx) + expf(u1 - mx));
    float2 r;
    r.x = u0 - lse;
    r.y = u1 - lse;
    *(float2*)(out + (size_t)gw * 2) = r;
  }
}

// ---------------- launch ----------------
extern "C" void kernel_launch(void* const* d_in, const int* in_sizes, int n_in,
                              void* d_out, int out_size, void* d_ws, size_t ws_size,
                              hipStream_t stream) {
  const float* x = (const float*)d_in[0];
  const int* ei = (const int*)d_in[1];
  const float* W = (const float*)d_in[2];
  const float* att_s_g = (const float*)d_in[3];
  const float* att_d_g = (const float*)d_in[4];
  const float* gbias = (const float*)d_in[5];
  const float* cw = (const float*)d_in[6];
  const float* cb = (const float*)d_in[7];
  const float* linW = (const float*)d_in[8];
  const float* linb = (const float*)d_in[9];
  float* out = (float*)d_out;

  const int n = in_sizes[0] / 256;   // 100000
  const int E = in_sizes[1] / 2;     // 300000
  const int tot = E + n;

  char* p = (char*)d_ws;
  auto alloc = [&](size_t bytes) -> char* {
    char* r = p;
    p += (bytes + 255) & ~(size_t)255;
    return r;
  };
  unsigned short* xwbf = (unsigned short*)alloc((size_t)n * 1024 * 2);
  unsigned short* xbf = (unsigned short*)alloc((size_t)n * 256 * 2);
  unsigned short* wtbf = (unsigned short*)alloc((size_t)1024 * 256 * 2);
  float* a_s = (float*)alloc((size_t)n * 4 * 4);
  float* a_d = (float*)alloc((size_t)n * 4 * 4);
  float* s_row = (float*)alloc((size_t)n * 4 * 4);
  float* denom = (float*)alloc((size_t)n * 4 * 4);
  float* num = (float*)alloc((size_t)n * 4 * 4);
  int* head = (int*)alloc((size_t)n * 4);
  int* nxt = (int*)alloc((size_t)E * 4);
  float* pooled = (float*)alloc(256);
  float* a4 = (float*)alloc(256);
  float* hb = (float*)alloc(256 * 4);
  float* hbuf = (float*)alloc((size_t)n * 256 * 4);

  int total8 = n * 256 / 8;
  k_conv_x<<<dim3((total8 + 255) / 256), dim3(256), 0, stream>>>(x, xbf, total8);
  k_wt<<<dim3(4), dim3(256), 0, stream>>>(W, wtbf);
  k_init<<<dim3((n * 4 + 255) / 256), dim3(256), 0, stream>>>(denom, num, head, pooled, n);
  k_link<<<dim3((E + 255) / 256), dim3(256), 0, stream>>>(ei, head, nxt, E);
  k_gemm<<<dim3((n + 127) / 128), dim3(256), 0, stream>>>(xbf, wtbf, att_s_g, att_d_g, xwbf, a_s, a_d, s_row, n);
  k_denom<<<dim3((tot + 255) / 256), dim3(256), 0, stream>>>(ei, a_s, a_d, s_row, denom, num, E, n);
  k_pool2<<<dim3(64), dim3(256), 0, stream>>>(denom, num, pooled, n);
  k_head<<<dim3(1), dim3(256), 0, stream>>>(pooled, gbias, cw, cb, a4, hb, n);
  k_fuse<<<dim3((n + 3) / 4), dim3(256), 0, stream>>>(ei, xwbf, a_s, a_d, denom, head, nxt, a4, hb, x, hbuf, n);
  k_out<<<dim3((E + 3) / 4), dim3(256), 0, stream>>>(ei, hbuf, linW, linb, out, E);
}